// Round 10
// baseline (705.345 us; speedup 1.0000x reference)
//
#include <hip/hip_runtime.h>
#include <math.h>

// VQ-VAE EMA vector quantizer, MI355X. Round 10: tail fix.
// (1) enorm maxes: wave-reduce before atomicMax (was 65K serialized atomics to
//     2 addresses ~ +100us, Guideline-12 violation introduced in round 7).
// (2) head unfused back to convert_x/convert_e/enorm (right-sized LDS).
// (3) update_embed 256->1024 blocks (4x TLP on ~100MB streaming).
// gemm (253us, proven) and rescore unchanged.
// Algorithm: single-pass f16 candidate GEMM (K=256) + certified exact fp32
// rescore. N=32768 rows, D=256, K=8192 codes.

#define KC 8192
#define DD 256
#define NV 32768

typedef _Float16 f16;
typedef _Float16 f16x8 __attribute__((ext_vector_type(8)));
typedef _Float16 f16x4 __attribute__((ext_vector_type(4)));
typedef float f32x4 __attribute__((ext_vector_type(4)));
typedef unsigned int u32;
typedef unsigned long long u64;

#define DBIAS 4096.0f

__device__ __forceinline__ u32 umin32(u32 a, u32 b) { return a < b ? a : b; }

// ---------- x NCHW fp32 -> xh/xl f16 [n][d], plus sum(x^2) ----------
__global__ __launch_bounds__(256, 2) void k_convert_x(
    const float* __restrict__ x, f16* __restrict__ xh, f16* __restrict__ xl,
    float* __restrict__ lossAcc) {
    __shared__ float xs[256][68];
    __shared__ float red[4];
    const int t = threadIdx.x;
    const int n0 = blockIdx.x * 64;
    const int b = n0 >> 10;
    const int h0 = (n0 >> 5) & 31;
    {
        const int p = t >> 7, tt = t & 127;
        const int wq = (tt & 7) * 4, d0 = tt >> 3;
        const float* src = x + (size_t)b * 262144 + (size_t)(h0 + p) * 32 + wq;
        float s2 = 0.f;
        #pragma unroll
        for (int i = 0; i < 16; ++i) {
            int d = d0 + i * 16;
            float4 v = *(const float4*)(src + (size_t)d * 1024);
            *(float4*)&xs[d][p * 32 + wq] = v;
            s2 += v.x * v.x + v.y * v.y + v.z * v.z + v.w * v.w;
        }
        for (int off = 32; off > 0; off >>= 1) s2 += __shfl_xor(s2, off);
        if ((t & 63) == 0) red[t >> 6] = s2;
    }
    __syncthreads();
    if (t == 0) atomicAdd(&lossAcc[1], red[0] + red[1] + red[2] + red[3]);
    {
        const int rr = t & 3, c = t >> 2;
        #pragma unroll
        for (int i = 0; i < 16; ++i) {
            int r = rr + i * 4;
            f16x4 hv, lv;
            #pragma unroll
            for (int q = 0; q < 4; ++q) {
                float v = xs[c * 4 + q][r];
                f16 h = (f16)v;
                float rem = v - (float)h;
                hv[q] = h; lv[q] = (f16)rem;
            }
            *(f16x4*)(xh + (size_t)(n0 + r) * DD + c * 4) = hv;
            *(f16x4*)(xl + (size_t)(n0 + r) * DD + c * 4) = lv;
        }
    }
}

// ---------- embed fp32 [d][k] -> eh/el f16 [k][d] (transposed, split) ----------
__global__ void k_convert_e(const float* __restrict__ embed,
                            f16* __restrict__ eh, f16* __restrict__ el) {
    int kt = blockIdx.x & 255, dt = blockIdx.x >> 8;
    int k0 = kt * 32, d0 = dt * 32;
    __shared__ float tile[32][33];
    int t = threadIdx.x;
    int kk = t & 31, ii = t >> 5;
    for (int p = 0; p < 4; ++p) {
        int d = ii + p * 8;
        tile[d][kk] = embed[(size_t)(d0 + d) * KC + k0 + kk];
    }
    __syncthreads();
    int dv = t & 31, kk2 = t >> 5;
    for (int p = 0; p < 4; ++p) {
        int k = kk2 + p * 8;
        float v = tile[dv][k];
        f16 h = (f16)v;
        float rem = v - (float)h;
        eh[(size_t)(k0 + k) * DD + d0 + dv] = h;
        el[(size_t)(k0 + k) * DD + d0 + dv] = (f16)rem;
    }
}

// ---------- enorm[k] = sum_d e^2 (exact) + global maxes (wave-reduced atomics) ----------
__global__ void k_enorm(const float* __restrict__ embed, float* __restrict__ enorm,
                        float* __restrict__ lossAcc) {
    int k = blockIdx.x * 256 + threadIdx.x;
    float s2 = 0.f, sl2 = 0.f;
    for (int d = 0; d < DD; ++d) {
        float v = embed[(size_t)d * KC + k];
        s2 += v * v;
        f16 h = (f16)v;
        float rem = v - (float)h;
        float lf = (float)((f16)rem);
        sl2 += lf * lf;
    }
    enorm[k] = s2;
    float m2 = s2, ml = sl2;
    for (int off = 32; off > 0; off >>= 1) {
        m2 = fmaxf(m2, __shfl_xor(m2, off));
        ml = fmaxf(ml, __shfl_xor(ml, off));
    }
    if ((threadIdx.x & 63) == 0) {
        // positive floats: int-bit compare == float compare
        atomicMax((int*)(lossAcc + 2), __float_as_int(m2));
        atomicMax((int*)(lossAcc + 3), __float_as_int(ml));
    }
}

// ---------- single-pass MFMA distance GEMM -> candidate table (UNCHANGED, 253us) ----------
// dapprox[n][k] = enorm[k] - 2*sum(xh*eh), K=256 (8 BK=32 tiles).
// Block 256x128, 8 waves as 4x2, per-wave 64x64. Superrow-swizzled LDS +
// gload_lds staging + XCD-chunked grid.
// Epilogue: top-2 per (row, 64-col subslab) via biased-positive uint keys,
// stored to cand[row][subslab].

__device__ __forceinline__ void gload16(const void* g, void* l) {
    __builtin_amdgcn_global_load_lds(
        (const __attribute__((address_space(1))) void*)g,
        (__attribute__((address_space(3))) void*)l, 16, 0, 0);
}

#define STAGE(KT, NB) do { \
    const f16* _ga = xh + aoff + (KT) * 32; \
    gload16(_ga, ldsAw + (NB) * 16384); \
    gload16(_ga + 16 * DD, ldsAw + (NB) * 16384 + 1024); \
    gload16(eh + boff + (KT) * 32, ldsBw + (NB) * 8192); \
} while (0)

#define BODY(KT, B, NB) do { \
    STAGE((KT) + 1, NB); \
    const char* _ab = AsB + (B) * 16384 + abyte; \
    const char* _bb = BsB + (B) * 8192 + bbyte; \
    f16x8 _b0 = *(const f16x8*)(_bb); \
    f16x8 _b1 = *(const f16x8*)(_bb + 1024); \
    f16x8 _b2 = *(const f16x8*)(_bb + 2048); \
    f16x8 _b3 = *(const f16x8*)(_bb + 3072); \
    _Pragma("unroll") for (int _i = 0; _i < 4; ++_i) { \
        f16x8 _a = *(const f16x8*)(_ab + _i * 1024); \
        __builtin_amdgcn_s_setprio(1); \
        acc[_i][0] = __builtin_amdgcn_mfma_f32_16x16x32_f16(_a, _b0, acc[_i][0], 0, 0, 0); \
        acc[_i][1] = __builtin_amdgcn_mfma_f32_16x16x32_f16(_a, _b1, acc[_i][1], 0, 0, 0); \
        acc[_i][2] = __builtin_amdgcn_mfma_f32_16x16x32_f16(_a, _b2, acc[_i][2], 0, 0, 0); \
        acc[_i][3] = __builtin_amdgcn_mfma_f32_16x16x32_f16(_a, _b3, acc[_i][3], 0, 0, 0); \
        __builtin_amdgcn_s_setprio(0); \
    } \
    __syncthreads(); \
} while (0)

#define FINALT(B) do { \
    const char* _ab = AsB + (B) * 16384 + abyte; \
    const char* _bb = BsB + (B) * 8192 + bbyte; \
    f16x8 _b0 = *(const f16x8*)(_bb); \
    f16x8 _b1 = *(const f16x8*)(_bb + 1024); \
    f16x8 _b2 = *(const f16x8*)(_bb + 2048); \
    f16x8 _b3 = *(const f16x8*)(_bb + 3072); \
    _Pragma("unroll") for (int _i = 0; _i < 4; ++_i) { \
        f16x8 _a = *(const f16x8*)(_ab + _i * 1024); \
        __builtin_amdgcn_s_setprio(1); \
        acc[_i][0] = __builtin_amdgcn_mfma_f32_16x16x32_f16(_a, _b0, acc[_i][0], 0, 0, 0); \
        acc[_i][1] = __builtin_amdgcn_mfma_f32_16x16x32_f16(_a, _b1, acc[_i][1], 0, 0, 0); \
        acc[_i][2] = __builtin_amdgcn_mfma_f32_16x16x32_f16(_a, _b2, acc[_i][2], 0, 0, 0); \
        acc[_i][3] = __builtin_amdgcn_mfma_f32_16x16x32_f16(_a, _b3, acc[_i][3], 0, 0, 0); \
        __builtin_amdgcn_s_setprio(0); \
    } \
} while (0)

__global__ __launch_bounds__(512, 4) void k_gemm_cand(
    const f16* __restrict__ xh, const f16* __restrict__ eh,
    const float* __restrict__ enorm, u64* __restrict__ cand) {
    __shared__ f16 As[2][8192];   // 2 x 16384 B: 256 rows x 32 f16 (superrow layout)
    __shared__ f16 Bs[2][4096];   // 2 x  8192 B: 128 rows x 32 f16
    __shared__ float en_s[128];

    const int t = threadIdx.x;
    const int lane = t & 63, wid = t >> 6;
    const int wr = wid >> 1, wc = wid & 1;           // 4 row-groups x 2 col-groups
    const int m = lane & 15, q = lane >> 4;

    // XCD-chunked dispatch (FETCH-proven map)
    const int bid = blockIdx.x;
    const int xcd = bid & 7, seq = bid >> 3;
    const int colb = seq >> 4;                 // 0..63
    const int rowb = (xcd << 4) | (seq & 15);  // 0..127
    const int BR = rowb * 256;
    const int CBb = colb * 128;

    char* AsB = (char*)&As[0][0];
    char* BsB = (char*)&Bs[0][0];

    // pre-biased: all distances become positive -> uint order == float order
    if (t < 128) en_s[t] = enorm[CBb + t] + DBIAS;

    // hoisted staging offsets (inverse superrow swizzle on global source)
    const int u8 = lane >> 3, cx = (lane & 7) ^ u8;
    const int stg_row = 2 * u8 + (cx >> 2);
    const int stg_col = (cx & 3) * 8;
    const size_t aoff = (size_t)(BR + wid * 32 + stg_row) * DD + stg_col;
    const size_t boff = (size_t)(CBb + wid * 16 + stg_row) * DD + stg_col;
    char* const ldsAw = AsB + wid * 2048;
    char* const ldsBw = BsB + wid * 1024;

    // hoisted read addresses (swizzled ds_read)
    const int rdsw = (((((m & 1) << 2) | q)) ^ (m >> 1)) * 16;
    const int abyte = wr * 4096 + (m >> 1) * 128 + rdsw;
    const int bbyte = wc * 4096 + (m >> 1) * 128 + rdsw;

    f32x4 acc[4][4];
    #pragma unroll
    for (int i = 0; i < 4; ++i)
        #pragma unroll
        for (int j = 0; j < 4; ++j) acc[i][j] = (f32x4){0.f, 0.f, 0.f, 0.f};

    STAGE(0, 0);
    __syncthreads();
    BODY(0, 0, 1); BODY(1, 1, 0); BODY(2, 0, 1); BODY(3, 1, 0);
    BODY(4, 0, 1); BODY(5, 1, 0); BODY(6, 0, 1);
    FINALT(1);

    // ---- epilogue: top-2 per (row, 64-col subslab); biased keys; [row][sslab] store ----
    const int sslab = colb * 2 + wc;
    float enb[4];
    #pragma unroll
    for (int j = 0; j < 4; ++j) enb[j] = en_s[wc * 64 + j * 16 + m];
    #pragma unroll
    for (int i = 0; i < 4; ++i)
    #pragma unroll
    for (int r = 0; r < 4; ++r) {
        u32 kk[4];
        #pragma unroll
        for (int j = 0; j < 4; ++j) {
            float dv = __builtin_fmaf(-2.f, acc[i][j][r], enb[j]);   // positive
            kk[j] = (__float_as_uint(dv) & 0xFFFFFFC0u) | (u32)(j * 16 + m);
        }
        // top-1 butterfly
        u32 g0 = umin32(umin32(kk[0], kk[1]), umin32(kk[2], kk[3]));
        #pragma unroll
        for (int h = 1; h < 16; h <<= 1)
            g0 = umin32(g0, (u32)__shfl_xor((int)g0, h));
        // masked second-best (keys unique: col in low bits)
        u32 l2 = 0xFFFFFFFFu;
        #pragma unroll
        for (int j = 0; j < 4; ++j) l2 = umin32(l2, kk[j] == g0 ? 0xFFFFFFFFu : kk[j]);
        u32 g1 = l2;
        #pragma unroll
        for (int h = 1; h < 16; h <<= 1)
            g1 = umin32(g1, (u32)__shfl_xor((int)g1, h));
        if (m == 0) {
            int row = BR + wr * 64 + i * 16 + q * 4 + r;
            cand[(size_t)row * 128 + sslab] = ((u64)g1 << 32) | g0;
        }
    }
}

// ---------- exact rescore of certified candidate window; emits idx/cnt/loss ----------
__global__ __launch_bounds__(256) void k_rescore(
    const u64* __restrict__ cand, const f16* __restrict__ xh, const f16* __restrict__ xl,
    const f16* __restrict__ eh, const f16* __restrict__ el,
    const float* __restrict__ enorm, int* __restrict__ idx, int* __restrict__ cnt,
    float* __restrict__ lossAcc) {
    __shared__ float lred[4];
    const int t = threadIdx.x, l = t & 63, w = t >> 6;
    const int n = blockIdx.x * 4 + w;
    const int l4 = l * 4;

    // coalesced: two contiguous 512B reads per wave
    u64 p0 = cand[(size_t)n * 128 + l];
    u64 p1 = cand[(size_t)n * 128 + 64 + l];
    u32 e0 = (u32)p0, e1 = (u32)(p0 >> 32), e2 = (u32)p1, e3 = (u32)(p1 >> 32);

    // global approx min (biased domain, floored keys)
    u32 mk = umin32(umin32(e0, e1), umin32(e2, e3));
    #pragma unroll
    for (int off = 1; off < 64; off <<= 1)
        mk = umin32(mk, (u32)__shfl_xor((int)mk, off));
    float gminb = __uint_as_float(mk & 0xFFFFFFC0u);   // biased value

    // x row + split norms
    f16x4 hv = *(const f16x4*)(xh + (size_t)n * DD + l4);
    f16x4 lv = *(const f16x4*)(xl + (size_t)n * DD + l4);
    float xf0 = (float)hv[0] + (float)lv[0];
    float xf1 = (float)hv[1] + (float)lv[1];
    float xf2 = (float)hv[2] + (float)lv[2];
    float xf3 = (float)hv[3] + (float)lv[3];
    float xh2 = (float)hv[0]*(float)hv[0] + (float)hv[1]*(float)hv[1]
              + (float)hv[2]*(float)hv[2] + (float)hv[3]*(float)hv[3];
    float xl2 = (float)lv[0]*(float)lv[0] + (float)lv[1]*(float)lv[1]
              + (float)lv[2]*(float)lv[2] + (float)lv[3]*(float)lv[3];
    #pragma unroll
    for (int off = 1; off < 64; off <<= 1) {
        xh2 += __shfl_xor(xh2, off);
        xl2 += __shfl_xor(xl2, off);
    }
    float maxE2 = lossAcc[2], maxEl2 = lossAcc[3];
    // |dapprox - dexact| <= 2(||xh||*||el|| + ||xl||*||e||) + rounding pads
    float dlt = 2.f * (sqrtf(xh2) * sqrtf(maxEl2) + sqrtf(xl2) * sqrtf(maxE2));
    float tau = gminb + 2.f * dlt * 1.02f + 0.2f;      // biased domain

    float best = 3.4e38f;
    int bestc = 1 << 30;

#define SLOT(ENT, SBASE) do { \
    float _av = __uint_as_float((ENT) & 0xFFFFFFC0u); \
    u64 _bm = __ballot(_av <= tau); \
    while (_bm) { \
        int _src = __ffsll((unsigned long long)_bm) - 1; _bm &= _bm - 1; \
        u32 _ee = (u32)__shfl((int)(ENT), _src); \
        int _code = ((SBASE) + _src) * 64 + (int)(_ee & 63u); \
        f16x4 _ah = *(const f16x4*)(eh + (size_t)_code * DD + l4); \
        f16x4 _al = *(const f16x4*)(el + (size_t)_code * DD + l4); \
        float _pt = xf0 * ((float)_ah[0] + (float)_al[0]) \
                  + xf1 * ((float)_ah[1] + (float)_al[1]) \
                  + xf2 * ((float)_ah[2] + (float)_al[2]) \
                  + xf3 * ((float)_ah[3] + (float)_al[3]); \
        _pt += __shfl_xor(_pt, 1);  _pt += __shfl_xor(_pt, 2); \
        _pt += __shfl_xor(_pt, 4);  _pt += __shfl_xor(_pt, 8); \
        _pt += __shfl_xor(_pt, 16); _pt += __shfl_xor(_pt, 32); \
        float _d = enorm[_code] - 2.f * _pt; \
        if (_d < best || (_d == best && _code < bestc)) { best = _d; bestc = _code; } \
    } \
} while (0)

    SLOT(e0, 0);
    SLOT(e1, 0);
    SLOT(e2, 64);
    SLOT(e3, 64);
#undef SLOT

    if (l == 0) {
        idx[n] = bestc;
        atomicAdd(&cnt[bestc], 1);
        lred[w] = best;
    }
    __syncthreads();
    if (t == 0) atomicAdd(&lossAcc[0], lred[0] + lred[1] + lred[2] + lred[3]);
}

// ---------- single-block stats ----------
__global__ void k_stats(const int* __restrict__ cnt, const float* __restrict__ cluster_size,
                        const float* __restrict__ lossAcc,
                        float* __restrict__ out_ncs, float* __restrict__ out_loss,
                        float* __restrict__ out_perp,
                        float* __restrict__ smoothed, int* __restrict__ offsets) {
    __shared__ float rn[256], rp[256];
    __shared__ int rc[256];
    __shared__ int base_s[256];
    int t = threadIdx.x;
    float s_n = 0.f, s_pl = 0.f;
    int s_c = 0;
    float ncs_loc[32];
    #pragma unroll
    for (int i = 0; i < 32; ++i) {
        int k = t * 32 + i;
        int ci = cnt[k];
        float c = (float)ci;
        float ncs = cluster_size[k] * 0.99f + 0.01f * c;
        out_ncs[k] = ncs;
        ncs_loc[i] = ncs;
        s_n += ncs;
        float p = c * (1.0f / 32768.0f);
        s_pl += p * logf(p + 1e-10f);
        s_c += ci;
    }
    rn[t] = s_n; rp[t] = s_pl; rc[t] = s_c;
    for (int off = 128; off > 0; off >>= 1) {
        __syncthreads();
        if (t < off) { rn[t] += rn[t + off]; rp[t] += rp[t + off]; }
    }
    __syncthreads();
    float ntot = rn[0];
    if (t == 0) {
        out_loss[0] = 0.25f * (lossAcc[0] + lossAcc[1]) * (1.0f / 8388608.0f);
        out_perp[0] = expf(-rp[0]);
    }
    #pragma unroll
    for (int i = 0; i < 32; ++i) {
        int k = t * 32 + i;
        float ncs = ncs_loc[i];
        smoothed[k] = ntot * (ncs + 1e-5f) / (ntot + ncs * 1e-5f);
    }
    __syncthreads();
    if (t == 0) {
        int run = 0;
        for (int qq = 0; qq < 256; ++qq) { base_s[qq] = run; run += rc[qq]; }
    }
    __syncthreads();
    int run = base_s[t];
    #pragma unroll
    for (int i = 0; i < 32; ++i) {
        int k = t * 32 + i;
        offsets[k] = run;
        run += cnt[k];
    }
}

// ---------- counting-sort scatter ----------
__global__ void k_scatter(const int* __restrict__ idx, const int* __restrict__ offsets,
                          int* __restrict__ cursor, int* __restrict__ order) {
    int n = blockIdx.x * 256 + threadIdx.x;
    int k = idx[n];
    int pos = offsets[k] + atomicAdd(&cursor[k], 1);
    order[pos] = n;
}

// ---------- dwT[k][d] (f16) = segment_sum of x ----------
__global__ void k_dw(const int* __restrict__ cnt, const int* __restrict__ offsets,
                     const int* __restrict__ order, const f16* __restrict__ xh,
                     const f16* __restrict__ xl, f16* __restrict__ dwT) {
    int k = blockIdx.x;
    int t = threadIdx.x;
    int c = cnt[k], base = offsets[k];
    float s = 0.f;
    for (int i = 0; i < c; ++i) {
        int n = order[base + i];
        s += (float)xh[(size_t)n * DD + t] + (float)xl[(size_t)n * DD + t];
    }
    dwT[(size_t)k * DD + t] = (f16)s;
}

// ---------- new_ema_embed / new_embed (1024 blocks, 8-d tiles: 4x TLP) ----------
__global__ void k_update_embed(const f16* __restrict__ dwT, const float* __restrict__ ema_embed,
                               const float* __restrict__ smoothed,
                               float* __restrict__ out_embed, float* __restrict__ out_ema) {
    __shared__ float tile[8][260];
    int bx = blockIdx.x, t = threadIdx.x;
    int d0 = (bx & 31) * 8, k0 = (bx >> 5) * 256;
    {
        f16x8 v = *(const f16x8*)(dwT + (size_t)(k0 + t) * DD + d0);
        #pragma unroll
        for (int j = 0; j < 8; ++j) tile[j][t] = (float)v[j];
    }
    __syncthreads();
    float sm = smoothed[k0 + t];
    #pragma unroll
    for (int dv = 0; dv < 8; ++dv) {
        size_t o = (size_t)(d0 + dv) * KC + k0 + t;
        float dw = tile[dv][t];
        float ne = ema_embed[o] * 0.99f + 0.01f * dw;
        out_ema[o] = ne;
        out_embed[o] = ne / sm;
    }
}

// ---------- quantize gather + NCHW writeback (overwrites cand table region) ----------
__global__ __launch_bounds__(256, 2) void k_quantize_out(
    const int* __restrict__ idx, const f16* __restrict__ eh, const f16* __restrict__ el,
    float* __restrict__ out) {
    __shared__ float qv[256][68];
    __shared__ int li[64];
    int t = threadIdx.x;
    int n0 = blockIdx.x * 64;
    int b = n0 >> 10, h0 = (n0 >> 5) & 31;
    if (t < 64) li[t] = idx[n0 + t];
    __syncthreads();
    {
        int r = t >> 2, dq4 = (t & 3) * 4;
        const f16* srch = eh + (size_t)li[r] * DD;
        const f16* srcl = el + (size_t)li[r] * DD;
        for (int i = 0; i < 16; ++i) {
            int d = dq4 + i * 16;
            f16x4 hv = *(const f16x4*)(srch + d);
            f16x4 lv = *(const f16x4*)(srcl + d);
            qv[d + 0][r] = (float)hv[0] + (float)lv[0];
            qv[d + 1][r] = (float)hv[1] + (float)lv[1];
            qv[d + 2][r] = (float)hv[2] + (float)lv[2];
            qv[d + 3][r] = (float)hv[3] + (float)lv[3];
        }
    }
    __syncthreads();
    {
        int p = t >> 7, tt = t & 127;
        int wq = (tt & 7) * 4, d0 = tt >> 3;
        float* dst = out + (size_t)b * 262144 + (size_t)(h0 + p) * 32 + wq;
        for (int i = 0; i < 16; ++i) {
            int d = d0 + i * 16;
            float4 v = *(const float4*)&qv[d][p * 32 + wq];
            *(float4*)(dst + (size_t)d * 1024) = v;
        }
    }
}

extern "C" void kernel_launch(void* const* d_in, const int* in_sizes, int n_in,
                              void* d_out, int out_size, void* d_ws, size_t ws_size,
                              hipStream_t stream) {
    (void)in_sizes; (void)n_in; (void)out_size; (void)ws_size;
    const float* x            = (const float*)d_in[0];
    const float* embed        = (const float*)d_in[1];
    const float* cluster_size = (const float*)d_in[2];
    const float* ema_embed    = (const float*)d_in[3];
    float* out = (float*)d_out;
    char* ws = (char*)d_ws;

    f16*   xh       = (f16*)  (ws + 0);           // 16,777,216
    f16*   xl       = (f16*)  (ws + 16777216);    // 16,777,216
    f16*   eh       = (f16*)  (ws + 33554432);    //  4,194,304
    f16*   el       = (f16*)  (ws + 37748736);    //  4,194,304
    float* enorm    = (float*)(ws + 41943040);    //     32,768
    float* smoothed = (float*)(ws + 41975808);    //     32,768
    int*   idx      = (int*)  (ws + 42008576);    //    131,072
    int*   cnt      = (int*)  (ws + 42139648);    //     32,768
    int*   cursor   = (int*)  (ws + 42172416);    //     32,768
    int*   offsets  = (int*)  (ws + 42205184);    //     32,768
    float* lossAcc  = (float*)(ws + 42237952);    //        256 (padded)
    int*   order    = (int*)  (ws + 42238208);    //    131,072
    f16*   dwT      = (f16*)  (ws + 42500352);    //  4,194,304  -> total 46,694,656

    // candidate table (32768 rows x 128 subslabs x u64 = 32MB) lives in the
    // out_q region of d_out — dead until k_quantize_out overwrites it.
    u64* cand = (u64*)d_out;

    float* out_q    = out;
    float* out_loss = out + 8388608;
    float* out_perp = out + 8388609;
    float* out_ncs  = out + 8388610;
    float* out_emb  = out + 8396802;
    float* out_ema  = out + 10493954;

    hipMemsetAsync(cnt, 0, 65536, stream);          // cnt + cursor adjacent
    hipMemsetAsync(lossAcc, 0, 16, stream);         // loss[0..1] + maxE2/maxEl2

    k_convert_x<<<512, 256, 0, stream>>>(x, xh, xl, lossAcc);
    k_convert_e<<<2048, 256, 0, stream>>>(embed, eh, el);
    k_enorm<<<32, 256, 0, stream>>>(embed, enorm, lossAcc);
    k_gemm_cand<<<8192, 512, 0, stream>>>(xh, eh, enorm, cand);
    k_rescore<<<8192, 256, 0, stream>>>(cand, xh, xl, eh, el, enorm, idx, cnt, lossAcc);
    k_stats<<<1, 256, 0, stream>>>(cnt, cluster_size, lossAcc, out_ncs, out_loss, out_perp,
                                   smoothed, offsets);
    k_scatter<<<128, 256, 0, stream>>>(idx, offsets, cursor, order);
    k_dw<<<8192, 256, 0, stream>>>(cnt, offsets, order, xh, xl, dwT);
    k_update_embed<<<1024, 256, 0, stream>>>(dwT, ema_embed, smoothed, out_emb, out_ema);
    k_quantize_out<<<512, 256, 0, stream>>>(idx, eh, el, out_q);
}

// Round 11
// 637.065 us; speedup vs baseline: 1.1072x; 1.1072x over previous
//
#include <hip/hip_runtime.h>
#include <math.h>

// VQ-VAE EMA vector quantizer, MI355X. Round 11:
// (1) gemm epilogue: __shfl (LDS-pipe ds_swizzle, 128/wave) -> DPP row_shr
//     min-merge (pure VALU, 0 LDS ops), store from lane m==15.
// (2) gemm K-loop: 3-buffer counted-vmcnt pipeline (WAITV(3) steady state,
//     raw barriers, stage 2 tiles ahead) -- kills the per-tile vmcnt(0) drain.
// (3) convert_e + enorm fused (embed read once, exact fp32 enorm, -1 launch).
// Algorithm: single-pass f16 candidate GEMM (K=256) + certified exact fp32
// rescore. N=32768 rows, D=256, K=8192 codes.

#define KC 8192
#define DD 256
#define NV 32768

typedef _Float16 f16;
typedef _Float16 f16x8 __attribute__((ext_vector_type(8)));
typedef _Float16 f16x4 __attribute__((ext_vector_type(4)));
typedef float f32x4 __attribute__((ext_vector_type(4)));
typedef unsigned int u32;
typedef unsigned long long u64;

#define DBIAS 4096.0f

__device__ __forceinline__ u32 umin32(u32 a, u32 b) { return a < b ? a : b; }
__device__ __forceinline__ u32 umax32(u32 a, u32 b) { return a > b ? a : b; }

// ---------- x NCHW fp32 -> xh/xl f16 [n][d], plus sum(x^2) ----------
__global__ __launch_bounds__(256, 2) void k_convert_x(
    const float* __restrict__ x, f16* __restrict__ xh, f16* __restrict__ xl,
    float* __restrict__ lossAcc) {
    __shared__ float xs[256][68];
    __shared__ float red[4];
    const int t = threadIdx.x;
    const int n0 = blockIdx.x * 64;
    const int b = n0 >> 10;
    const int h0 = (n0 >> 5) & 31;
    {
        const int p = t >> 7, tt = t & 127;
        const int wq = (tt & 7) * 4, d0 = tt >> 3;
        const float* src = x + (size_t)b * 262144 + (size_t)(h0 + p) * 32 + wq;
        float s2 = 0.f;
        #pragma unroll
        for (int i = 0; i < 16; ++i) {
            int d = d0 + i * 16;
            float4 v = *(const float4*)(src + (size_t)d * 1024);
            *(float4*)&xs[d][p * 32 + wq] = v;
            s2 += v.x * v.x + v.y * v.y + v.z * v.z + v.w * v.w;
        }
        for (int off = 32; off > 0; off >>= 1) s2 += __shfl_xor(s2, off);
        if ((t & 63) == 0) red[t >> 6] = s2;
    }
    __syncthreads();
    if (t == 0) atomicAdd(&lossAcc[1], red[0] + red[1] + red[2] + red[3]);
    {
        const int rr = t & 3, c = t >> 2;
        #pragma unroll
        for (int i = 0; i < 16; ++i) {
            int r = rr + i * 4;
            f16x4 hv, lv;
            #pragma unroll
            for (int q = 0; q < 4; ++q) {
                float v = xs[c * 4 + q][r];
                f16 h = (f16)v;
                float rem = v - (float)h;
                hv[q] = h; lv[q] = (f16)rem;
            }
            *(f16x4*)(xh + (size_t)(n0 + r) * DD + c * 4) = hv;
            *(f16x4*)(xl + (size_t)(n0 + r) * DD + c * 4) = lv;
        }
    }
}

// ---------- fused: embed fp32 [d][k] -> eh/el f16 [k][d] + exact enorm + maxes ----------
// block = 32 codes x all 256 d. Thread: code c = t&31, d-group g = t>>5 (32 d's).
__global__ __launch_bounds__(256, 2) void k_convert_e(
    const float* __restrict__ embed, f16* __restrict__ eh, f16* __restrict__ el,
    float* __restrict__ enorm, float* __restrict__ lossAcc) {
    __shared__ float ps2[8][33];
    __shared__ float psl[8][33];
    const int t = threadIdx.x;
    const int c = t & 31, g = t >> 5;
    const int k = blockIdx.x * 32 + c;
    const int d0 = g * 32;
    f16x8 hv[4], lv[4];
    float s2 = 0.f, sl2 = 0.f;
    #pragma unroll
    for (int i = 0; i < 32; ++i) {
        float v = embed[(size_t)(d0 + i) * KC + k];
        f16 h = (f16)v;
        float rem = v - (float)h;
        f16 lo = (f16)rem;
        hv[i >> 3][i & 7] = h;
        lv[i >> 3][i & 7] = lo;
        s2 += v * v;
        float lf = (float)lo;
        sl2 += lf * lf;
    }
    #pragma unroll
    for (int i = 0; i < 4; ++i) {
        *(f16x8*)(eh + (size_t)k * DD + d0 + i * 8) = hv[i];
        *(f16x8*)(el + (size_t)k * DD + d0 + i * 8) = lv[i];
    }
    ps2[g][c] = s2; psl[g][c] = sl2;
    __syncthreads();
    if (t < 32) {
        float e = 0.f, l = 0.f;
        #pragma unroll
        for (int g2 = 0; g2 < 8; ++g2) { e += ps2[g2][t]; l += psl[g2][t]; }
        enorm[blockIdx.x * 32 + t] = e;
        float me = e, mll = l;
        #pragma unroll
        for (int off = 16; off > 0; off >>= 1) {
            me = fmaxf(me, __shfl_xor(me, off));
            mll = fmaxf(mll, __shfl_xor(mll, off));
        }
        if (t == 0) {
            // positive floats: int-bit compare == float compare
            atomicMax((int*)(lossAcc + 2), __float_as_int(me));
            atomicMax((int*)(lossAcc + 3), __float_as_int(mll));
        }
    }
}

// ---------- single-pass MFMA distance GEMM -> candidate table ----------
// dapprox[n][k] = enorm[k] - 2*sum(xh*eh), K=256 (8 BK=32 tiles).
// Block 256x128, 8 waves as 4x2, per-wave 64x64. Superrow-swizzled LDS +
// gload_lds staging + XCD-chunked grid. 3-buffer counted-vmcnt pipeline:
// read(buf kt%3) -> lgkm0 -> bar -> stage(kt+2) -> MFMA -> vmcnt(3) -> bar.
// Epilogue: top-2 per (row, 64-col subslab) via DPP row_shr merge (no LDS pipe),
// biased-positive uint keys, stored to cand[row][subslab].

__device__ __forceinline__ void gload16(const void* g, void* l) {
    __builtin_amdgcn_global_load_lds(
        (const __attribute__((address_space(1))) void*)g,
        (__attribute__((address_space(3))) void*)l, 16, 0, 0);
}

#define CFENCE asm volatile("" ::: "memory")
#define BAR()  do { CFENCE; __builtin_amdgcn_s_barrier(); CFENCE; } while (0)
#define WAITV(N) asm volatile("s_waitcnt vmcnt(" #N ")" ::: "memory")
#define WAITL0   asm volatile("s_waitcnt lgkmcnt(0)" ::: "memory")

#define STAGE(KT, NB) do { \
    const f16* _ga = xh + aoff + (KT) * 32; \
    gload16(_ga, ldsAw + (NB) * 16384); \
    gload16(_ga + 16 * DD, ldsAw + (NB) * 16384 + 1024); \
    gload16(eh + boff + (KT) * 32, ldsBw + (NB) * 8192); \
} while (0)

// one K-tile: B = read buffer (kt%3); DOSTAGE -> STAGE(SKT, SNB); WN = vmcnt arg
#define PHASE(B, DOSTAGE, SKT, SNB, WN) do { \
    const char* _ab = AsB + (B) * 16384 + abyte; \
    const char* _bb = BsB + (B) * 8192 + bbyte; \
    f16x8 _aav[4], _bbv[4]; \
    _Pragma("unroll") for (int _j = 0; _j < 4; ++_j) _bbv[_j] = *(const f16x8*)(_bb + _j * 1024); \
    _Pragma("unroll") for (int _i = 0; _i < 4; ++_i) _aav[_i] = *(const f16x8*)(_ab + _i * 1024); \
    WAITL0; BAR(); \
    if (DOSTAGE) { STAGE(SKT, SNB); } \
    __builtin_amdgcn_s_setprio(1); \
    _Pragma("unroll") for (int _i = 0; _i < 4; ++_i) \
    _Pragma("unroll") for (int _j = 0; _j < 4; ++_j) \
        acc[_i][_j] = __builtin_amdgcn_mfma_f32_16x16x32_f16(_aav[_i], _bbv[_j], acc[_i][_j], 0, 0, 0); \
    __builtin_amdgcn_s_setprio(0); \
    asm volatile("s_waitcnt vmcnt(" #WN ")" ::: "memory"); BAR(); \
} while (0)

#define PFINAL(B) do { \
    const char* _ab = AsB + (B) * 16384 + abyte; \
    const char* _bb = BsB + (B) * 8192 + bbyte; \
    f16x8 _aav[4], _bbv[4]; \
    _Pragma("unroll") for (int _j = 0; _j < 4; ++_j) _bbv[_j] = *(const f16x8*)(_bb + _j * 1024); \
    _Pragma("unroll") for (int _i = 0; _i < 4; ++_i) _aav[_i] = *(const f16x8*)(_ab + _i * 1024); \
    WAITL0; \
    __builtin_amdgcn_s_setprio(1); \
    _Pragma("unroll") for (int _i = 0; _i < 4; ++_i) \
    _Pragma("unroll") for (int _j = 0; _j < 4; ++_j) \
        acc[_i][_j] = __builtin_amdgcn_mfma_f32_16x16x32_f16(_aav[_i], _bbv[_j], acc[_i][_j], 0, 0, 0); \
    __builtin_amdgcn_s_setprio(0); \
} while (0)

// sorted top-2 pair merge over 16 m-lanes via DPP row_shr (bound_ctrl keeps own
// value -> idempotent merge at low lanes; full result lands at row-lane 15)
#define DPPSTEP(CTRL) do { \
    u32 _b0 = (u32)__builtin_amdgcn_update_dpp((int)a0v, (int)a0v, CTRL, 0xF, 0xF, false); \
    u32 _b1 = (u32)__builtin_amdgcn_update_dpp((int)a1v, (int)a1v, CTRL, 0xF, 0xF, false); \
    u32 _mx = umax32(a0v, _b0); \
    a0v = umin32(a0v, _b0); \
    a1v = umin32(_mx, umin32(a1v, _b1)); \
} while (0)

__global__ __launch_bounds__(512, 4) void k_gemm_cand(
    const f16* __restrict__ xh, const f16* __restrict__ eh,
    const float* __restrict__ enorm, u64* __restrict__ cand) {
    __shared__ f16 As[3][8192];   // 3 buffers x 16384 B: 256 rows x 32 f16 (superrow)
    __shared__ f16 Bs[3][4096];   // 3 buffers x  8192 B: 128 rows x 32 f16
    __shared__ float en_s[128];

    const int t = threadIdx.x;
    const int lane = t & 63, wid = t >> 6;
    const int wr = wid >> 1, wc = wid & 1;           // 4 row-groups x 2 col-groups
    const int m = lane & 15, q = lane >> 4;

    // XCD-chunked dispatch (FETCH-proven map)
    const int bid = blockIdx.x;
    const int xcd = bid & 7, seq = bid >> 3;
    const int colb = seq >> 4;                 // 0..63
    const int rowb = (xcd << 4) | (seq & 15);  // 0..127
    const int BR = rowb * 256;
    const int CBb = colb * 128;

    char* AsB = (char*)&As[0][0];
    char* BsB = (char*)&Bs[0][0];

    // en_s FIRST (its implicit vmcnt wait must precede the stage issues)
    if (t < 128) en_s[t] = enorm[CBb + t] + DBIAS;   // biased positive

    // hoisted staging offsets (inverse superrow swizzle on global source)
    const int u8 = lane >> 3, cx = (lane & 7) ^ u8;
    const int stg_row = 2 * u8 + (cx >> 2);
    const int stg_col = (cx & 3) * 8;
    const size_t aoff = (size_t)(BR + wid * 32 + stg_row) * DD + stg_col;
    const size_t boff = (size_t)(CBb + wid * 16 + stg_row) * DD + stg_col;
    char* const ldsAw = AsB + wid * 2048;
    char* const ldsBw = BsB + wid * 1024;

    // hoisted read addresses (swizzled ds_read)
    const int rdsw = (((((m & 1) << 2) | q)) ^ (m >> 1)) * 16;
    const int abyte = wr * 4096 + (m >> 1) * 128 + rdsw;
    const int bbyte = wc * 4096 + (m >> 1) * 128 + rdsw;

    f32x4 acc[4][4];
    #pragma unroll
    for (int i = 0; i < 4; ++i)
        #pragma unroll
        for (int j = 0; j < 4; ++j) acc[i][j] = (f32x4){0.f, 0.f, 0.f, 0.f};

    // prologue: stage tiles 0,1; confirm tile 0 (WAITV(3) also retires en_s load)
    STAGE(0, 0); STAGE(1, 1);
    WAITV(3); BAR();

    // tiles 0..7, buf = kt%3; stage kt+2 two tiles ahead; WAITV(3) steady state
    PHASE(0, 1, 2, 2, 3);
    PHASE(1, 1, 3, 0, 3);
    PHASE(2, 1, 4, 1, 3);
    PHASE(0, 1, 5, 2, 3);
    PHASE(1, 1, 6, 0, 3);
    PHASE(2, 1, 7, 1, 3);
    PHASE(0, 0, 0, 0, 0);
    PFINAL(1);

    // ---- epilogue: top-2 per (row, 64-col subslab) via DPP; [row][sslab] store ----
    const int sslab = colb * 2 + wc;
    float enb[4];
    #pragma unroll
    for (int j = 0; j < 4; ++j) enb[j] = en_s[wc * 64 + j * 16 + m];
    #pragma unroll
    for (int i = 0; i < 4; ++i)
    #pragma unroll
    for (int r = 0; r < 4; ++r) {
        u32 kk[4];
        #pragma unroll
        for (int j = 0; j < 4; ++j) {
            float dv = __builtin_fmaf(-2.f, acc[i][j][r], enb[j]);   // positive
            kk[j] = (__float_as_uint(dv) & 0xFFFFFFC0u) | (u32)(j * 16 + m);
        }
        u32 s1 = umin32(kk[0], kk[1]), g1 = umax32(kk[0], kk[1]);
        u32 s2 = umin32(kk[2], kk[3]), g2 = umax32(kk[2], kk[3]);
        u32 a0v = umin32(s1, s2);
        u32 a1v = umin32(umax32(s1, s2), umin32(g1, g2));
        DPPSTEP(0x111);   // row_shr:1
        DPPSTEP(0x112);   // row_shr:2
        DPPSTEP(0x114);   // row_shr:4
        DPPSTEP(0x118);   // row_shr:8  -> full top-2 at row-lane 15
        if (m == 15) {
            int row = BR + wr * 64 + i * 16 + q * 4 + r;
            cand[(size_t)row * 128 + sslab] = ((u64)a1v << 32) | a0v;
        }
    }
}

// ---------- exact rescore of certified candidate window; emits idx/cnt/loss ----------
__global__ __launch_bounds__(256) void k_rescore(
    const u64* __restrict__ cand, const f16* __restrict__ xh, const f16* __restrict__ xl,
    const f16* __restrict__ eh, const f16* __restrict__ el,
    const float* __restrict__ enorm, int* __restrict__ idx, int* __restrict__ cnt,
    float* __restrict__ lossAcc) {
    __shared__ float lred[4];
    const int t = threadIdx.x, l = t & 63, w = t >> 6;
    const int n = blockIdx.x * 4 + w;
    const int l4 = l * 4;

    // coalesced: two contiguous 512B reads per wave
    u64 p0 = cand[(size_t)n * 128 + l];
    u64 p1 = cand[(size_t)n * 128 + 64 + l];
    u32 e0 = (u32)p0, e1 = (u32)(p0 >> 32), e2 = (u32)p1, e3 = (u32)(p1 >> 32);

    // global approx min (biased domain, floored keys)
    u32 mk = umin32(umin32(e0, e1), umin32(e2, e3));
    #pragma unroll
    for (int off = 1; off < 64; off <<= 1)
        mk = umin32(mk, (u32)__shfl_xor((int)mk, off));
    float gminb = __uint_as_float(mk & 0xFFFFFFC0u);   // biased value

    // x row + split norms
    f16x4 hv = *(const f16x4*)(xh + (size_t)n * DD + l4);
    f16x4 lv = *(const f16x4*)(xl + (size_t)n * DD + l4);
    float xf0 = (float)hv[0] + (float)lv[0];
    float xf1 = (float)hv[1] + (float)lv[1];
    float xf2 = (float)hv[2] + (float)lv[2];
    float xf3 = (float)hv[3] + (float)lv[3];
    float xh2 = (float)hv[0]*(float)hv[0] + (float)hv[1]*(float)hv[1]
              + (float)hv[2]*(float)hv[2] + (float)hv[3]*(float)hv[3];
    float xl2 = (float)lv[0]*(float)lv[0] + (float)lv[1]*(float)lv[1]
              + (float)lv[2]*(float)lv[2] + (float)lv[3]*(float)lv[3];
    #pragma unroll
    for (int off = 1; off < 64; off <<= 1) {
        xh2 += __shfl_xor(xh2, off);
        xl2 += __shfl_xor(xl2, off);
    }
    float maxE2 = lossAcc[2], maxEl2 = lossAcc[3];
    // |dapprox - dexact| <= 2(||xh||*||el|| + ||xl||*||e||) + rounding pads
    float dlt = 2.f * (sqrtf(xh2) * sqrtf(maxEl2) + sqrtf(xl2) * sqrtf(maxE2));
    float tau = gminb + 2.f * dlt * 1.02f + 0.2f;      // biased domain

    float best = 3.4e38f;
    int bestc = 1 << 30;

#define SLOT(ENT, SBASE) do { \
    float _av = __uint_as_float((ENT) & 0xFFFFFFC0u); \
    u64 _bm = __ballot(_av <= tau); \
    while (_bm) { \
        int _src = __ffsll((unsigned long long)_bm) - 1; _bm &= _bm - 1; \
        u32 _ee = (u32)__shfl((int)(ENT), _src); \
        int _code = ((SBASE) + _src) * 64 + (int)(_ee & 63u); \
        f16x4 _ah = *(const f16x4*)(eh + (size_t)_code * DD + l4); \
        f16x4 _al = *(const f16x4*)(el + (size_t)_code * DD + l4); \
        float _pt = xf0 * ((float)_ah[0] + (float)_al[0]) \
                  + xf1 * ((float)_ah[1] + (float)_al[1]) \
                  + xf2 * ((float)_ah[2] + (float)_al[2]) \
                  + xf3 * ((float)_ah[3] + (float)_al[3]); \
        _pt += __shfl_xor(_pt, 1);  _pt += __shfl_xor(_pt, 2); \
        _pt += __shfl_xor(_pt, 4);  _pt += __shfl_xor(_pt, 8); \
        _pt += __shfl_xor(_pt, 16); _pt += __shfl_xor(_pt, 32); \
        float _d = enorm[_code] - 2.f * _pt; \
        if (_d < best || (_d == best && _code < bestc)) { best = _d; bestc = _code; } \
    } \
} while (0)

    SLOT(e0, 0);
    SLOT(e1, 0);
    SLOT(e2, 64);
    SLOT(e3, 64);
#undef SLOT

    if (l == 0) {
        idx[n] = bestc;
        atomicAdd(&cnt[bestc], 1);
        lred[w] = best;
    }
    __syncthreads();
    if (t == 0) atomicAdd(&lossAcc[0], lred[0] + lred[1] + lred[2] + lred[3]);
}

// ---------- single-block stats ----------
__global__ void k_stats(const int* __restrict__ cnt, const float* __restrict__ cluster_size,
                        const float* __restrict__ lossAcc,
                        float* __restrict__ out_ncs, float* __restrict__ out_loss,
                        float* __restrict__ out_perp,
                        float* __restrict__ smoothed, int* __restrict__ offsets) {
    __shared__ float rn[256], rp[256];
    __shared__ int rc[256];
    __shared__ int base_s[256];
    int t = threadIdx.x;
    float s_n = 0.f, s_pl = 0.f;
    int s_c = 0;
    float ncs_loc[32];
    #pragma unroll
    for (int i = 0; i < 32; ++i) {
        int k = t * 32 + i;
        int ci = cnt[k];
        float c = (float)ci;
        float ncs = cluster_size[k] * 0.99f + 0.01f * c;
        out_ncs[k] = ncs;
        ncs_loc[i] = ncs;
        s_n += ncs;
        float p = c * (1.0f / 32768.0f);
        s_pl += p * logf(p + 1e-10f);
        s_c += ci;
    }
    rn[t] = s_n; rp[t] = s_pl; rc[t] = s_c;
    for (int off = 128; off > 0; off >>= 1) {
        __syncthreads();
        if (t < off) { rn[t] += rn[t + off]; rp[t] += rp[t + off]; }
    }
    __syncthreads();
    float ntot = rn[0];
    if (t == 0) {
        out_loss[0] = 0.25f * (lossAcc[0] + lossAcc[1]) * (1.0f / 8388608.0f);
        out_perp[0] = expf(-rp[0]);
    }
    #pragma unroll
    for (int i = 0; i < 32; ++i) {
        int k = t * 32 + i;
        float ncs = ncs_loc[i];
        smoothed[k] = ntot * (ncs + 1e-5f) / (ntot + ncs * 1e-5f);
    }
    __syncthreads();
    if (t == 0) {
        int run = 0;
        for (int qq = 0; qq < 256; ++qq) { base_s[qq] = run; run += rc[qq]; }
    }
    __syncthreads();
    int run = base_s[t];
    #pragma unroll
    for (int i = 0; i < 32; ++i) {
        int k = t * 32 + i;
        offsets[k] = run;
        run += cnt[k];
    }
}

// ---------- counting-sort scatter ----------
__global__ void k_scatter(const int* __restrict__ idx, const int* __restrict__ offsets,
                          int* __restrict__ cursor, int* __restrict__ order) {
    int n = blockIdx.x * 256 + threadIdx.x;
    int k = idx[n];
    int pos = offsets[k] + atomicAdd(&cursor[k], 1);
    order[pos] = n;
}

// ---------- dwT[k][d] (f16) = segment_sum of x ----------
__global__ void k_dw(const int* __restrict__ cnt, const int* __restrict__ offsets,
                     const int* __restrict__ order, const f16* __restrict__ xh,
                     const f16* __restrict__ xl, f16* __restrict__ dwT) {
    int k = blockIdx.x;
    int t = threadIdx.x;
    int c = cnt[k], base = offsets[k];
    float s = 0.f;
    for (int i = 0; i < c; ++i) {
        int n = order[base + i];
        s += (float)xh[(size_t)n * DD + t] + (float)xl[(size_t)n * DD + t];
    }
    dwT[(size_t)k * DD + t] = (f16)s;
}

// ---------- new_ema_embed / new_embed (1024 blocks, 8-d tiles) ----------
__global__ void k_update_embed(const f16* __restrict__ dwT, const float* __restrict__ ema_embed,
                               const float* __restrict__ smoothed,
                               float* __restrict__ out_embed, float* __restrict__ out_ema) {
    __shared__ float tile[8][260];
    int bx = blockIdx.x, t = threadIdx.x;
    int d0 = (bx & 31) * 8, k0 = (bx >> 5) * 256;
    {
        f16x8 v = *(const f16x8*)(dwT + (size_t)(k0 + t) * DD + d0);
        #pragma unroll
        for (int j = 0; j < 8; ++j) tile[j][t] = (float)v[j];
    }
    __syncthreads();
    float sm = smoothed[k0 + t];
    #pragma unroll
    for (int dv = 0; dv < 8; ++dv) {
        size_t o = (size_t)(d0 + dv) * KC + k0 + t;
        float dw = tile[dv][t];
        float ne = ema_embed[o] * 0.99f + 0.01f * dw;
        out_ema[o] = ne;
        out_embed[o] = ne / sm;
    }
}

// ---------- quantize gather + NCHW writeback (overwrites cand table region) ----------
__global__ __launch_bounds__(256, 2) void k_quantize_out(
    const int* __restrict__ idx, const f16* __restrict__ eh, const f16* __restrict__ el,
    float* __restrict__ out) {
    __shared__ float qv[256][68];
    __shared__ int li[64];
    int t = threadIdx.x;
    int n0 = blockIdx.x * 64;
    int b = n0 >> 10, h0 = (n0 >> 5) & 31;
    if (t < 64) li[t] = idx[n0 + t];
    __syncthreads();
    {
        int r = t >> 2, dq4 = (t & 3) * 4;
        const f16* srch = eh + (size_t)li[r] * DD;
        const f16* srcl = el + (size_t)li[r] * DD;
        for (int i = 0; i < 16; ++i) {
            int d = dq4 + i * 16;
            f16x4 hv = *(const f16x4*)(srch + d);
            f16x4 lv = *(const f16x4*)(srcl + d);
            qv[d + 0][r] = (float)hv[0] + (float)lv[0];
            qv[d + 1][r] = (float)hv[1] + (float)lv[1];
            qv[d + 2][r] = (float)hv[2] + (float)lv[2];
            qv[d + 3][r] = (float)hv[3] + (float)lv[3];
        }
    }
    __syncthreads();
    {
        int p = t >> 7, tt = t & 127;
        int wq = (tt & 7) * 4, d0 = tt >> 3;
        float* dst = out + (size_t)b * 262144 + (size_t)(h0 + p) * 32 + wq;
        for (int i = 0; i < 16; ++i) {
            int d = d0 + i * 16;
            float4 v = *(const float4*)&qv[d][p * 32 + wq];
            *(float4*)(dst + (size_t)d * 1024) = v;
        }
    }
}

extern "C" void kernel_launch(void* const* d_in, const int* in_sizes, int n_in,
                              void* d_out, int out_size, void* d_ws, size_t ws_size,
                              hipStream_t stream) {
    (void)in_sizes; (void)n_in; (void)out_size; (void)ws_size;
    const float* x            = (const float*)d_in[0];
    const float* embed        = (const float*)d_in[1];
    const float* cluster_size = (const float*)d_in[2];
    const float* ema_embed    = (const float*)d_in[3];
    float* out = (float*)d_out;
    char* ws = (char*)d_ws;

    f16*   xh       = (f16*)  (ws + 0);           // 16,777,216
    f16*   xl       = (f16*)  (ws + 16777216);    // 16,777,216
    f16*   eh       = (f16*)  (ws + 33554432);    //  4,194,304
    f16*   el       = (f16*)  (ws + 37748736);    //  4,194,304
    float* enorm    = (float*)(ws + 41943040);    //     32,768
    float* smoothed = (float*)(ws + 41975808);    //     32,768
    int*   idx      = (int*)  (ws + 42008576);    //    131,072
    int*   cnt      = (int*)  (ws + 42139648);    //     32,768
    int*   cursor   = (int*)  (ws + 42172416);    //     32,768
    int*   offsets  = (int*)  (ws + 42205184);    //     32,768
    float* lossAcc  = (float*)(ws + 42237952);    //        256 (padded)
    int*   order    = (int*)  (ws + 42238208);    //    131,072
    f16*   dwT      = (f16*)  (ws + 42500352);    //  4,194,304  -> total 46,694,656

    // candidate table (32768 rows x 128 subslabs x u64 = 32MB) lives in the
    // out_q region of d_out — dead until k_quantize_out overwrites it.
    u64* cand = (u64*)d_out;

    float* out_q    = out;
    float* out_loss = out + 8388608;
    float* out_perp = out + 8388609;
    float* out_ncs  = out + 8388610;
    float* out_emb  = out + 8396802;
    float* out_ema  = out + 10493954;

    hipMemsetAsync(cnt, 0, 65536, stream);          // cnt + cursor adjacent
    hipMemsetAsync(lossAcc, 0, 16, stream);         // loss[0..1] + maxE2/maxEl2

    k_convert_x<<<512, 256, 0, stream>>>(x, xh, xl, lossAcc);
    k_convert_e<<<256, 256, 0, stream>>>(embed, eh, el, enorm, lossAcc);
    k_gemm_cand<<<8192, 512, 0, stream>>>(xh, eh, enorm, cand);
    k_rescore<<<8192, 256, 0, stream>>>(cand, xh, xl, eh, el, enorm, idx, cnt, lossAcc);
    k_stats<<<1, 256, 0, stream>>>(cnt, cluster_size, lossAcc, out_ncs, out_loss, out_perp,
                                   smoothed, offsets);
    k_scatter<<<128, 256, 0, stream>>>(idx, offsets, cursor, order);
    k_dw<<<8192, 256, 0, stream>>>(cnt, offsets, order, xh, xl, dwT);
    k_update_embed<<<1024, 256, 0, stream>>>(dwT, ema_embed, smoothed, out_emb, out_ema);
    k_quantize_out<<<512, 256, 0, stream>>>(idx, eh, el, out_q);
}

// Round 12
// 500.483 us; speedup vs baseline: 1.4093x; 1.2729x over previous
//
#include <hip/hip_runtime.h>
#include <math.h>

// VQ-VAE EMA vector quantizer, MI355X. Round 12: k_dw load-imbalance fix.
// k_dw was 202us at 0.9% VALUBusy / 3.7% occupancy -- serial per-code row walk,
// hottest code (~600 rows) dominated. Now: 8 waves per code (rows strided mod 8),
// f16x4 lanes over d, unroll-2 independent accumulators, LDS reduce. ~600 -> ~75
// chain iterations. Everything else unchanged from round 11 (637us total).
// Algorithm: single-pass f16 candidate GEMM (K=256) + certified exact fp32
// rescore. N=32768 rows, D=256, K=8192 codes.

#define KC 8192
#define DD 256
#define NV 32768

typedef _Float16 f16;
typedef _Float16 f16x8 __attribute__((ext_vector_type(8)));
typedef _Float16 f16x4 __attribute__((ext_vector_type(4)));
typedef float f32x4 __attribute__((ext_vector_type(4)));
typedef unsigned int u32;
typedef unsigned long long u64;

#define DBIAS 4096.0f

__device__ __forceinline__ u32 umin32(u32 a, u32 b) { return a < b ? a : b; }
__device__ __forceinline__ u32 umax32(u32 a, u32 b) { return a > b ? a : b; }

// ---------- x NCHW fp32 -> xh/xl f16 [n][d], plus sum(x^2) ----------
__global__ __launch_bounds__(256, 2) void k_convert_x(
    const float* __restrict__ x, f16* __restrict__ xh, f16* __restrict__ xl,
    float* __restrict__ lossAcc) {
    __shared__ float xs[256][68];
    __shared__ float red[4];
    const int t = threadIdx.x;
    const int n0 = blockIdx.x * 64;
    const int b = n0 >> 10;
    const int h0 = (n0 >> 5) & 31;
    {
        const int p = t >> 7, tt = t & 127;
        const int wq = (tt & 7) * 4, d0 = tt >> 3;
        const float* src = x + (size_t)b * 262144 + (size_t)(h0 + p) * 32 + wq;
        float s2 = 0.f;
        #pragma unroll
        for (int i = 0; i < 16; ++i) {
            int d = d0 + i * 16;
            float4 v = *(const float4*)(src + (size_t)d * 1024);
            *(float4*)&xs[d][p * 32 + wq] = v;
            s2 += v.x * v.x + v.y * v.y + v.z * v.z + v.w * v.w;
        }
        for (int off = 32; off > 0; off >>= 1) s2 += __shfl_xor(s2, off);
        if ((t & 63) == 0) red[t >> 6] = s2;
    }
    __syncthreads();
    if (t == 0) atomicAdd(&lossAcc[1], red[0] + red[1] + red[2] + red[3]);
    {
        const int rr = t & 3, c = t >> 2;
        #pragma unroll
        for (int i = 0; i < 16; ++i) {
            int r = rr + i * 4;
            f16x4 hv, lv;
            #pragma unroll
            for (int q = 0; q < 4; ++q) {
                float v = xs[c * 4 + q][r];
                f16 h = (f16)v;
                float rem = v - (float)h;
                hv[q] = h; lv[q] = (f16)rem;
            }
            *(f16x4*)(xh + (size_t)(n0 + r) * DD + c * 4) = hv;
            *(f16x4*)(xl + (size_t)(n0 + r) * DD + c * 4) = lv;
        }
    }
}

// ---------- fused: embed fp32 [d][k] -> eh/el f16 [k][d] + exact enorm + maxes ----------
__global__ __launch_bounds__(256, 2) void k_convert_e(
    const float* __restrict__ embed, f16* __restrict__ eh, f16* __restrict__ el,
    float* __restrict__ enorm, float* __restrict__ lossAcc) {
    __shared__ float ps2[8][33];
    __shared__ float psl[8][33];
    const int t = threadIdx.x;
    const int c = t & 31, g = t >> 5;
    const int k = blockIdx.x * 32 + c;
    const int d0 = g * 32;
    f16x8 hv[4], lv[4];
    float s2 = 0.f, sl2 = 0.f;
    #pragma unroll
    for (int i = 0; i < 32; ++i) {
        float v = embed[(size_t)(d0 + i) * KC + k];
        f16 h = (f16)v;
        float rem = v - (float)h;
        f16 lo = (f16)rem;
        hv[i >> 3][i & 7] = h;
        lv[i >> 3][i & 7] = lo;
        s2 += v * v;
        float lf = (float)lo;
        sl2 += lf * lf;
    }
    #pragma unroll
    for (int i = 0; i < 4; ++i) {
        *(f16x8*)(eh + (size_t)k * DD + d0 + i * 8) = hv[i];
        *(f16x8*)(el + (size_t)k * DD + d0 + i * 8) = lv[i];
    }
    ps2[g][c] = s2; psl[g][c] = sl2;
    __syncthreads();
    if (t < 32) {
        float e = 0.f, l = 0.f;
        #pragma unroll
        for (int g2 = 0; g2 < 8; ++g2) { e += ps2[g2][t]; l += psl[g2][t]; }
        enorm[blockIdx.x * 32 + t] = e;
        float me = e, mll = l;
        #pragma unroll
        for (int off = 16; off > 0; off >>= 1) {
            me = fmaxf(me, __shfl_xor(me, off));
            mll = fmaxf(mll, __shfl_xor(mll, off));
        }
        if (t == 0) {
            // positive floats: int-bit compare == float compare
            atomicMax((int*)(lossAcc + 2), __float_as_int(me));
            atomicMax((int*)(lossAcc + 3), __float_as_int(mll));
        }
    }
}

// ---------- single-pass MFMA distance GEMM -> candidate table ----------
// dapprox[n][k] = enorm[k] - 2*sum(xh*eh), K=256 (8 BK=32 tiles).
// Block 256x128, 8 waves as 4x2, per-wave 64x64. Superrow-swizzled LDS +
// gload_lds staging + XCD-chunked grid. 3-buffer counted-vmcnt pipeline.
// Epilogue: top-2 per (row, 64-col subslab) via DPP row_shr merge,
// biased-positive uint keys, stored to cand[row][subslab].

__device__ __forceinline__ void gload16(const void* g, void* l) {
    __builtin_amdgcn_global_load_lds(
        (const __attribute__((address_space(1))) void*)g,
        (__attribute__((address_space(3))) void*)l, 16, 0, 0);
}

#define CFENCE asm volatile("" ::: "memory")
#define BAR()  do { CFENCE; __builtin_amdgcn_s_barrier(); CFENCE; } while (0)
#define WAITV(N) asm volatile("s_waitcnt vmcnt(" #N ")" ::: "memory")
#define WAITL0   asm volatile("s_waitcnt lgkmcnt(0)" ::: "memory")

#define STAGE(KT, NB) do { \
    const f16* _ga = xh + aoff + (KT) * 32; \
    gload16(_ga, ldsAw + (NB) * 16384); \
    gload16(_ga + 16 * DD, ldsAw + (NB) * 16384 + 1024); \
    gload16(eh + boff + (KT) * 32, ldsBw + (NB) * 8192); \
} while (0)

// one K-tile: B = read buffer (kt%3); DOSTAGE -> STAGE(SKT, SNB); WN = vmcnt arg
#define PHASE(B, DOSTAGE, SKT, SNB, WN) do { \
    const char* _ab = AsB + (B) * 16384 + abyte; \
    const char* _bb = BsB + (B) * 8192 + bbyte; \
    f16x8 _aav[4], _bbv[4]; \
    _Pragma("unroll") for (int _j = 0; _j < 4; ++_j) _bbv[_j] = *(const f16x8*)(_bb + _j * 1024); \
    _Pragma("unroll") for (int _i = 0; _i < 4; ++_i) _aav[_i] = *(const f16x8*)(_ab + _i * 1024); \
    WAITL0; BAR(); \
    if (DOSTAGE) { STAGE(SKT, SNB); } \
    __builtin_amdgcn_s_setprio(1); \
    _Pragma("unroll") for (int _i = 0; _i < 4; ++_i) \
    _Pragma("unroll") for (int _j = 0; _j < 4; ++_j) \
        acc[_i][_j] = __builtin_amdgcn_mfma_f32_16x16x32_f16(_aav[_i], _bbv[_j], acc[_i][_j], 0, 0, 0); \
    __builtin_amdgcn_s_setprio(0); \
    asm volatile("s_waitcnt vmcnt(" #WN ")" ::: "memory"); BAR(); \
} while (0)

#define PFINAL(B) do { \
    const char* _ab = AsB + (B) * 16384 + abyte; \
    const char* _bb = BsB + (B) * 8192 + bbyte; \
    f16x8 _aav[4], _bbv[4]; \
    _Pragma("unroll") for (int _j = 0; _j < 4; ++_j) _bbv[_j] = *(const f16x8*)(_bb + _j * 1024); \
    _Pragma("unroll") for (int _i = 0; _i < 4; ++_i) _aav[_i] = *(const f16x8*)(_ab + _i * 1024); \
    WAITL0; \
    __builtin_amdgcn_s_setprio(1); \
    _Pragma("unroll") for (int _i = 0; _i < 4; ++_i) \
    _Pragma("unroll") for (int _j = 0; _j < 4; ++_j) \
        acc[_i][_j] = __builtin_amdgcn_mfma_f32_16x16x32_f16(_aav[_i], _bbv[_j], acc[_i][_j], 0, 0, 0); \
    __builtin_amdgcn_s_setprio(0); \
} while (0)

// sorted top-2 pair merge over 16 m-lanes via DPP row_shr (bound_ctrl keeps own
// value -> idempotent merge at low lanes; full result lands at row-lane 15)
#define DPPSTEP(CTRL) do { \
    u32 _b0 = (u32)__builtin_amdgcn_update_dpp((int)a0v, (int)a0v, CTRL, 0xF, 0xF, false); \
    u32 _b1 = (u32)__builtin_amdgcn_update_dpp((int)a1v, (int)a1v, CTRL, 0xF, 0xF, false); \
    u32 _mx = umax32(a0v, _b0); \
    a0v = umin32(a0v, _b0); \
    a1v = umin32(_mx, umin32(a1v, _b1)); \
} while (0)

__global__ __launch_bounds__(512, 4) void k_gemm_cand(
    const f16* __restrict__ xh, const f16* __restrict__ eh,
    const float* __restrict__ enorm, u64* __restrict__ cand) {
    __shared__ f16 As[3][8192];   // 3 buffers x 16384 B: 256 rows x 32 f16 (superrow)
    __shared__ f16 Bs[3][4096];   // 3 buffers x  8192 B: 128 rows x 32 f16
    __shared__ float en_s[128];

    const int t = threadIdx.x;
    const int lane = t & 63, wid = t >> 6;
    const int wr = wid >> 1, wc = wid & 1;           // 4 row-groups x 2 col-groups
    const int m = lane & 15, q = lane >> 4;

    // XCD-chunked dispatch (FETCH-proven map)
    const int bid = blockIdx.x;
    const int xcd = bid & 7, seq = bid >> 3;
    const int colb = seq >> 4;                 // 0..63
    const int rowb = (xcd << 4) | (seq & 15);  // 0..127
    const int BR = rowb * 256;
    const int CBb = colb * 128;

    char* AsB = (char*)&As[0][0];
    char* BsB = (char*)&Bs[0][0];

    // en_s FIRST (its implicit vmcnt wait must precede the stage issues)
    if (t < 128) en_s[t] = enorm[CBb + t] + DBIAS;   // biased positive

    // hoisted staging offsets (inverse superrow swizzle on global source)
    const int u8 = lane >> 3, cx = (lane & 7) ^ u8;
    const int stg_row = 2 * u8 + (cx >> 2);
    const int stg_col = (cx & 3) * 8;
    const size_t aoff = (size_t)(BR + wid * 32 + stg_row) * DD + stg_col;
    const size_t boff = (size_t)(CBb + wid * 16 + stg_row) * DD + stg_col;
    char* const ldsAw = AsB + wid * 2048;
    char* const ldsBw = BsB + wid * 1024;

    // hoisted read addresses (swizzled ds_read)
    const int rdsw = (((((m & 1) << 2) | q)) ^ (m >> 1)) * 16;
    const int abyte = wr * 4096 + (m >> 1) * 128 + rdsw;
    const int bbyte = wc * 4096 + (m >> 1) * 128 + rdsw;

    f32x4 acc[4][4];
    #pragma unroll
    for (int i = 0; i < 4; ++i)
        #pragma unroll
        for (int j = 0; j < 4; ++j) acc[i][j] = (f32x4){0.f, 0.f, 0.f, 0.f};

    // prologue: stage tiles 0,1; confirm tile 0 (WAITV(3) also retires en_s load)
    STAGE(0, 0); STAGE(1, 1);
    WAITV(3); BAR();

    // tiles 0..7, buf = kt%3; stage kt+2 two tiles ahead; WAITV(3) steady state
    PHASE(0, 1, 2, 2, 3);
    PHASE(1, 1, 3, 0, 3);
    PHASE(2, 1, 4, 1, 3);
    PHASE(0, 1, 5, 2, 3);
    PHASE(1, 1, 6, 0, 3);
    PHASE(2, 1, 7, 1, 3);
    PHASE(0, 0, 0, 0, 0);
    PFINAL(1);

    // ---- epilogue: top-2 per (row, 64-col subslab) via DPP; [row][sslab] store ----
    const int sslab = colb * 2 + wc;
    float enb[4];
    #pragma unroll
    for (int j = 0; j < 4; ++j) enb[j] = en_s[wc * 64 + j * 16 + m];
    #pragma unroll
    for (int i = 0; i < 4; ++i)
    #pragma unroll
    for (int r = 0; r < 4; ++r) {
        u32 kk[4];
        #pragma unroll
        for (int j = 0; j < 4; ++j) {
            float dv = __builtin_fmaf(-2.f, acc[i][j][r], enb[j]);   // positive
            kk[j] = (__float_as_uint(dv) & 0xFFFFFFC0u) | (u32)(j * 16 + m);
        }
        u32 s1 = umin32(kk[0], kk[1]), g1 = umax32(kk[0], kk[1]);
        u32 s2 = umin32(kk[2], kk[3]), g2 = umax32(kk[2], kk[3]);
        u32 a0v = umin32(s1, s2);
        u32 a1v = umin32(umax32(s1, s2), umin32(g1, g2));
        DPPSTEP(0x111);   // row_shr:1
        DPPSTEP(0x112);   // row_shr:2
        DPPSTEP(0x114);   // row_shr:4
        DPPSTEP(0x118);   // row_shr:8  -> full top-2 at row-lane 15
        if (m == 15) {
            int row = BR + wr * 64 + i * 16 + q * 4 + r;
            cand[(size_t)row * 128 + sslab] = ((u64)a1v << 32) | a0v;
        }
    }
}

// ---------- exact rescore of certified candidate window; emits idx/cnt/loss ----------
__global__ __launch_bounds__(256) void k_rescore(
    const u64* __restrict__ cand, const f16* __restrict__ xh, const f16* __restrict__ xl,
    const f16* __restrict__ eh, const f16* __restrict__ el,
    const float* __restrict__ enorm, int* __restrict__ idx, int* __restrict__ cnt,
    float* __restrict__ lossAcc) {
    __shared__ float lred[4];
    const int t = threadIdx.x, l = t & 63, w = t >> 6;
    const int n = blockIdx.x * 4 + w;
    const int l4 = l * 4;

    // coalesced: two contiguous 512B reads per wave
    u64 p0 = cand[(size_t)n * 128 + l];
    u64 p1 = cand[(size_t)n * 128 + 64 + l];
    u32 e0 = (u32)p0, e1 = (u32)(p0 >> 32), e2 = (u32)p1, e3 = (u32)(p1 >> 32);

    // global approx min (biased domain, floored keys)
    u32 mk = umin32(umin32(e0, e1), umin32(e2, e3));
    #pragma unroll
    for (int off = 1; off < 64; off <<= 1)
        mk = umin32(mk, (u32)__shfl_xor((int)mk, off));
    float gminb = __uint_as_float(mk & 0xFFFFFFC0u);   // biased value

    // x row + split norms
    f16x4 hv = *(const f16x4*)(xh + (size_t)n * DD + l4);
    f16x4 lv = *(const f16x4*)(xl + (size_t)n * DD + l4);
    float xf0 = (float)hv[0] + (float)lv[0];
    float xf1 = (float)hv[1] + (float)lv[1];
    float xf2 = (float)hv[2] + (float)lv[2];
    float xf3 = (float)hv[3] + (float)lv[3];
    float xh2 = (float)hv[0]*(float)hv[0] + (float)hv[1]*(float)hv[1]
              + (float)hv[2]*(float)hv[2] + (float)hv[3]*(float)hv[3];
    float xl2 = (float)lv[0]*(float)lv[0] + (float)lv[1]*(float)lv[1]
              + (float)lv[2]*(float)lv[2] + (float)lv[3]*(float)lv[3];
    #pragma unroll
    for (int off = 1; off < 64; off <<= 1) {
        xh2 += __shfl_xor(xh2, off);
        xl2 += __shfl_xor(xl2, off);
    }
    float maxE2 = lossAcc[2], maxEl2 = lossAcc[3];
    // |dapprox - dexact| <= 2(||xh||*||el|| + ||xl||*||e||) + rounding pads
    float dlt = 2.f * (sqrtf(xh2) * sqrtf(maxEl2) + sqrtf(xl2) * sqrtf(maxE2));
    float tau = gminb + 2.f * dlt * 1.02f + 0.2f;      // biased domain

    float best = 3.4e38f;
    int bestc = 1 << 30;

#define SLOT(ENT, SBASE) do { \
    float _av = __uint_as_float((ENT) & 0xFFFFFFC0u); \
    u64 _bm = __ballot(_av <= tau); \
    while (_bm) { \
        int _src = __ffsll((unsigned long long)_bm) - 1; _bm &= _bm - 1; \
        u32 _ee = (u32)__shfl((int)(ENT), _src); \
        int _code = ((SBASE) + _src) * 64 + (int)(_ee & 63u); \
        f16x4 _ah = *(const f16x4*)(eh + (size_t)_code * DD + l4); \
        f16x4 _al = *(const f16x4*)(el + (size_t)_code * DD + l4); \
        float _pt = xf0 * ((float)_ah[0] + (float)_al[0]) \
                  + xf1 * ((float)_ah[1] + (float)_al[1]) \
                  + xf2 * ((float)_ah[2] + (float)_al[2]) \
                  + xf3 * ((float)_ah[3] + (float)_al[3]); \
        _pt += __shfl_xor(_pt, 1);  _pt += __shfl_xor(_pt, 2); \
        _pt += __shfl_xor(_pt, 4);  _pt += __shfl_xor(_pt, 8); \
        _pt += __shfl_xor(_pt, 16); _pt += __shfl_xor(_pt, 32); \
        float _d = enorm[_code] - 2.f * _pt; \
        if (_d < best || (_d == best && _code < bestc)) { best = _d; bestc = _code; } \
    } \
} while (0)

    SLOT(e0, 0);
    SLOT(e1, 0);
    SLOT(e2, 64);
    SLOT(e3, 64);
#undef SLOT

    if (l == 0) {
        idx[n] = bestc;
        atomicAdd(&cnt[bestc], 1);
        lred[w] = best;
    }
    __syncthreads();
    if (t == 0) atomicAdd(&lossAcc[0], lred[0] + lred[1] + lred[2] + lred[3]);
}

// ---------- single-block stats ----------
__global__ void k_stats(const int* __restrict__ cnt, const float* __restrict__ cluster_size,
                        const float* __restrict__ lossAcc,
                        float* __restrict__ out_ncs, float* __restrict__ out_loss,
                        float* __restrict__ out_perp,
                        float* __restrict__ smoothed, int* __restrict__ offsets) {
    __shared__ float rn[256], rp[256];
    __shared__ int rc[256];
    __shared__ int base_s[256];
    int t = threadIdx.x;
    float s_n = 0.f, s_pl = 0.f;
    int s_c = 0;
    float ncs_loc[32];
    #pragma unroll
    for (int i = 0; i < 32; ++i) {
        int k = t * 32 + i;
        int ci = cnt[k];
        float c = (float)ci;
        float ncs = cluster_size[k] * 0.99f + 0.01f * c;
        out_ncs[k] = ncs;
        ncs_loc[i] = ncs;
        s_n += ncs;
        float p = c * (1.0f / 32768.0f);
        s_pl += p * logf(p + 1e-10f);
        s_c += ci;
    }
    rn[t] = s_n; rp[t] = s_pl; rc[t] = s_c;
    for (int off = 128; off > 0; off >>= 1) {
        __syncthreads();
        if (t < off) { rn[t] += rn[t + off]; rp[t] += rp[t + off]; }
    }
    __syncthreads();
    float ntot = rn[0];
    if (t == 0) {
        out_loss[0] = 0.25f * (lossAcc[0] + lossAcc[1]) * (1.0f / 8388608.0f);
        out_perp[0] = expf(-rp[0]);
    }
    #pragma unroll
    for (int i = 0; i < 32; ++i) {
        int k = t * 32 + i;
        float ncs = ncs_loc[i];
        smoothed[k] = ntot * (ncs + 1e-5f) / (ntot + ncs * 1e-5f);
    }
    __syncthreads();
    if (t == 0) {
        int run = 0;
        for (int qq = 0; qq < 256; ++qq) { base_s[qq] = run; run += rc[qq]; }
    }
    __syncthreads();
    int run = base_s[t];
    #pragma unroll
    for (int i = 0; i < 32; ++i) {
        int k = t * 32 + i;
        offsets[k] = run;
        run += cnt[k];
    }
}

// ---------- counting-sort scatter ----------
__global__ void k_scatter(const int* __restrict__ idx, const int* __restrict__ offsets,
                          int* __restrict__ cursor, int* __restrict__ order) {
    int n = blockIdx.x * 256 + threadIdx.x;
    int k = idx[n];
    int pos = offsets[k] + atomicAdd(&cursor[k], 1);
    order[pos] = n;
}

// ---------- dwT[k][d] (f16) = segment_sum of x ----------
// 8 waves per code (rows strided mod 8); lane covers 4 d's (f16x4, coalesced
// 512B/row); unroll-2 independent accumulators; LDS partial reduce.
__global__ __launch_bounds__(512) void k_dw(
    const int* __restrict__ cnt, const int* __restrict__ offsets,
    const int* __restrict__ order, const f16* __restrict__ xh,
    const f16* __restrict__ xl, f16* __restrict__ dwT) {
    __shared__ float part[8][256];
    const int k = blockIdx.x;
    const int t = threadIdx.x, lane = t & 63, w = t >> 6;
    const int c = cnt[k], base = offsets[k];
    const int dq = lane * 4;
    f32x4 sa = (f32x4){0.f, 0.f, 0.f, 0.f};
    f32x4 sb = (f32x4){0.f, 0.f, 0.f, 0.f};
    for (int i = w; i < c; i += 16) {
        const int i2 = i + 8;
        const int n0 = order[base + i];
        const int n1 = (i2 < c) ? order[base + i2] : n0;
        f16x4 h0 = *(const f16x4*)(xh + (size_t)n0 * DD + dq);
        f16x4 l0 = *(const f16x4*)(xl + (size_t)n0 * DD + dq);
        f16x4 h1 = *(const f16x4*)(xh + (size_t)n1 * DD + dq);
        f16x4 l1 = *(const f16x4*)(xl + (size_t)n1 * DD + dq);
        #pragma unroll
        for (int j = 0; j < 4; ++j) sa[j] += (float)h0[j] + (float)l0[j];
        if (i2 < c) {   // wave-uniform branch (i, c uniform across wave)
            #pragma unroll
            for (int j = 0; j < 4; ++j) sb[j] += (float)h1[j] + (float)l1[j];
        }
    }
    #pragma unroll
    for (int j = 0; j < 4; ++j) part[w][dq + j] = sa[j] + sb[j];
    __syncthreads();
    if (t < 256) {
        float s = 0.f;
        #pragma unroll
        for (int w2 = 0; w2 < 8; ++w2) s += part[w2][t];
        dwT[(size_t)k * DD + t] = (f16)s;
    }
}

// ---------- new_ema_embed / new_embed (1024 blocks, 8-d tiles) ----------
__global__ void k_update_embed(const f16* __restrict__ dwT, const float* __restrict__ ema_embed,
                               const float* __restrict__ smoothed,
                               float* __restrict__ out_embed, float* __restrict__ out_ema) {
    __shared__ float tile[8][260];
    int bx = blockIdx.x, t = threadIdx.x;
    int d0 = (bx & 31) * 8, k0 = (bx >> 5) * 256;
    {
        f16x8 v = *(const f16x8*)(dwT + (size_t)(k0 + t) * DD + d0);
        #pragma unroll
        for (int j = 0; j < 8; ++j) tile[j][t] = (float)v[j];
    }
    __syncthreads();
    float sm = smoothed[k0 + t];
    #pragma unroll
    for (int dv = 0; dv < 8; ++dv) {
        size_t o = (size_t)(d0 + dv) * KC + k0 + t;
        float dw = tile[dv][t];
        float ne = ema_embed[o] * 0.99f + 0.01f * dw;
        out_ema[o] = ne;
        out_embed[o] = ne / sm;
    }
}

// ---------- quantize gather + NCHW writeback (overwrites cand table region) ----------
__global__ __launch_bounds__(256, 2) void k_quantize_out(
    const int* __restrict__ idx, const f16* __restrict__ eh, const f16* __restrict__ el,
    float* __restrict__ out) {
    __shared__ float qv[256][68];
    __shared__ int li[64];
    int t = threadIdx.x;
    int n0 = blockIdx.x * 64;
    int b = n0 >> 10, h0 = (n0 >> 5) & 31;
    if (t < 64) li[t] = idx[n0 + t];
    __syncthreads();
    {
        int r = t >> 2, dq4 = (t & 3) * 4;
        const f16* srch = eh + (size_t)li[r] * DD;
        const f16* srcl = el + (size_t)li[r] * DD;
        for (int i = 0; i < 16; ++i) {
            int d = dq4 + i * 16;
            f16x4 hv = *(const f16x4*)(srch + d);
            f16x4 lv = *(const f16x4*)(srcl + d);
            qv[d + 0][r] = (float)hv[0] + (float)lv[0];
            qv[d + 1][r] = (float)hv[1] + (float)lv[1];
            qv[d + 2][r] = (float)hv[2] + (float)lv[2];
            qv[d + 3][r] = (float)hv[3] + (float)lv[3];
        }
    }
    __syncthreads();
    {
        int p = t >> 7, tt = t & 127;
        int wq = (tt & 7) * 4, d0 = tt >> 3;
        float* dst = out + (size_t)b * 262144 + (size_t)(h0 + p) * 32 + wq;
        for (int i = 0; i < 16; ++i) {
            int d = d0 + i * 16;
            float4 v = *(const float4*)&qv[d][p * 32 + wq];
            *(float4*)(dst + (size_t)d * 1024) = v;
        }
    }
}

extern "C" void kernel_launch(void* const* d_in, const int* in_sizes, int n_in,
                              void* d_out, int out_size, void* d_ws, size_t ws_size,
                              hipStream_t stream) {
    (void)in_sizes; (void)n_in; (void)out_size; (void)ws_size;
    const float* x            = (const float*)d_in[0];
    const float* embed        = (const float*)d_in[1];
    const float* cluster_size = (const float*)d_in[2];
    const float* ema_embed    = (const float*)d_in[3];
    float* out = (float*)d_out;
    char* ws = (char*)d_ws;

    f16*   xh       = (f16*)  (ws + 0);           // 16,777,216
    f16*   xl       = (f16*)  (ws + 16777216);    // 16,777,216
    f16*   eh       = (f16*)  (ws + 33554432);    //  4,194,304
    f16*   el       = (f16*)  (ws + 37748736);    //  4,194,304
    float* enorm    = (float*)(ws + 41943040);    //     32,768
    float* smoothed = (float*)(ws + 41975808);    //     32,768
    int*   idx      = (int*)  (ws + 42008576);    //    131,072
    int*   cnt      = (int*)  (ws + 42139648);    //     32,768
    int*   cursor   = (int*)  (ws + 42172416);    //     32,768
    int*   offsets  = (int*)  (ws + 42205184);    //     32,768
    float* lossAcc  = (float*)(ws + 42237952);    //        256 (padded)
    int*   order    = (int*)  (ws + 42238208);    //    131,072
    f16*   dwT      = (f16*)  (ws + 42500352);    //  4,194,304  -> total 46,694,656

    // candidate table (32768 rows x 128 subslabs x u64 = 32MB) lives in the
    // out_q region of d_out — dead until k_quantize_out overwrites it.
    u64* cand = (u64*)d_out;

    float* out_q    = out;
    float* out_loss = out + 8388608;
    float* out_perp = out + 8388609;
    float* out_ncs  = out + 8388610;
    float* out_emb  = out + 8396802;
    float* out_ema  = out + 10493954;

    hipMemsetAsync(cnt, 0, 65536, stream);          // cnt + cursor adjacent
    hipMemsetAsync(lossAcc, 0, 16, stream);         // loss[0..1] + maxE2/maxEl2

    k_convert_x<<<512, 256, 0, stream>>>(x, xh, xl, lossAcc);
    k_convert_e<<<256, 256, 0, stream>>>(embed, eh, el, enorm, lossAcc);
    k_gemm_cand<<<8192, 512, 0, stream>>>(xh, eh, enorm, cand);
    k_rescore<<<8192, 256, 0, stream>>>(cand, xh, xl, eh, el, enorm, idx, cnt, lossAcc);
    k_stats<<<1, 256, 0, stream>>>(cnt, cluster_size, lossAcc, out_ncs, out_loss, out_perp,
                                   smoothed, offsets);
    k_scatter<<<128, 256, 0, stream>>>(idx, offsets, cursor, order);
    k_dw<<<8192, 512, 0, stream>>>(cnt, offsets, order, xh, xl, dwT);
    k_update_embed<<<1024, 256, 0, stream>>>(dwT, ema_embed, smoothed, out_emb, out_ema);
    k_quantize_out<<<512, 256, 0, stream>>>(idx, eh, el, out_q);
}